// Round 1
// baseline (215.263 us; speedup 1.0000x reference)
//
#include <hip/hip_runtime.h>

// ---------------------------------------------------------------------------
// keypoint_embedding: fp32 baseline (correctness anchor)
//   x(16,64,16) -> emb0(1024,128) -> emb1(1024,256) -> emb2(1024,512)
//   -> emb3(1024,1024) -> AB(1024,1024) [A=cols 0..511, B=cols 512..1023]
//   -> msum(16,512) = sum_{i,j} relu(B[b,i,c]+A[b,j,c]+b1[c])
//   -> out(16,2048) = msum/4096 @ w2^T + b2
// ---------------------------------------------------------------------------

__global__ __launch_bounds__(256) void k_embed(
    const float* __restrict__ x,
    const float* __restrict__ e1w, const float* __restrict__ e1b,
    const float* __restrict__ e2w, const float* __restrict__ e2b,
    float* __restrict__ emb0)
{
    int idx = blockIdx.x * 256 + threadIdx.x;   // 1024*128 total
    int row = idx >> 7, o = idx & 127;
    const float* xr = x + row * 16;
    float s1 = e1b[o] + xr[0] * e1w[o * 3 + 0] + xr[1] * e1w[o * 3 + 1] + xr[2] * e1w[o * 3 + 2];
    float s2 = e2b[o];
#pragma unroll
    for (int k = 0; k < 13; ++k) s2 += xr[3 + k] * e2w[o * 13 + k];
    emb0[row * 128 + o] = fmaxf(s1, 0.f) + fmaxf(s2, 0.f);
}

// C[m,n] = act( sum_k A[m,k] * Wrow(n)[k] + bias[n] )
// Wrow(n) = W + n*ldw            (n <  n_split)
//         = W + (n-n_split)*ldw + split_off   (n >= n_split)
// 64x64 tile, 256 threads, 4x4 per thread, K-chunk 16.
__global__ __launch_bounds__(256) void k_gemm(
    const float* __restrict__ A, const float* __restrict__ W,
    const float* __restrict__ bias, float* __restrict__ C,
    int K, int N, int ldw, int n_split, int split_off, int relu)
{
    __shared__ float As[16][68];   // [k][m], padded stride 68 (16B-aligned, 2-way max)
    __shared__ float Ws[16][68];   // [k][n]
    int tid = threadIdx.x;
    int tx = tid & 15, ty = tid >> 4;
    int m0 = blockIdx.x * 64, n0 = blockIdx.y * 64;

    int r  = tid >> 2;             // 0..63 : row of the tile this thread stages
    int kq = (tid & 3) * 4;        // 0,4,8,12 : k-offset (float4)
    int n = n0 + r;
    const float* wrow = W + (size_t)((n < n_split) ? n * ldw
                                                   : (n - n_split) * ldw + split_off);
    const float* arow = A + (size_t)(m0 + r) * K;

    float acc[4][4] = {};
    for (int k0 = 0; k0 < K; k0 += 16) {
        float4 va = *(const float4*)(arow + k0 + kq);
        float4 vw = *(const float4*)(wrow + k0 + kq);
        As[kq + 0][r] = va.x; As[kq + 1][r] = va.y; As[kq + 2][r] = va.z; As[kq + 3][r] = va.w;
        Ws[kq + 0][r] = vw.x; Ws[kq + 1][r] = vw.y; Ws[kq + 2][r] = vw.z; Ws[kq + 3][r] = vw.w;
        __syncthreads();
#pragma unroll
        for (int k = 0; k < 16; ++k) {
            float4 a = *(const float4*)&As[k][ty * 4];
            float4 w = *(const float4*)&Ws[k][tx * 4];
            float av[4] = {a.x, a.y, a.z, a.w};
            float wv[4] = {w.x, w.y, w.z, w.w};
#pragma unroll
            for (int i = 0; i < 4; ++i)
#pragma unroll
                for (int j = 0; j < 4; ++j) acc[i][j] += av[i] * wv[j];
        }
        __syncthreads();
    }

#pragma unroll
    for (int i = 0; i < 4; ++i) {
#pragma unroll
        for (int j = 0; j < 4; ++j) {
            int cn = n0 + tx * 4 + j;
            float v = acc[i][j] + (bias ? bias[cn] : 0.f);
            if (relu) v = fmaxf(v, 0.f);
            C[(size_t)(m0 + ty * 4 + i) * N + cn] = v;
        }
    }
}

// msum[b,c] += sum over i in [z*16,z*16+16), j in [0,64) of relu(B[b,i,c]+A[b,j,c]+b1[c])
// AB: A = cols [0,512), B = cols [512,1024) of the (1024,1024) buffer.
__global__ __launch_bounds__(256) void k_pairmean(
    const float* __restrict__ AB, const float* __restrict__ b1,
    float* __restrict__ msum)
{
    __shared__ float sA[64 * 64];
    __shared__ float sB[16 * 64];
    __shared__ float sb1[64];
    __shared__ float sPart[4][64];
    int t = threadIdx.x;
    int b = blockIdx.x, c0 = blockIdx.y * 64, z = blockIdx.z;
    int cl = t & 63, ig = t >> 6;

#pragma unroll
    for (int rep = 0; rep < 4; ++rep) {           // A tile: 64 rows x 64 cols
        int lin = rep * 256 + t;
        int j = lin >> 4, cq = (lin & 15) * 4;
        float4 v = *(const float4*)(AB + (size_t)(b * 64 + j) * 1024 + c0 + cq);
        *(float4*)&sA[j * 64 + cq] = v;
    }
    {                                             // B tile: 16 rows x 64 cols
        int i = t >> 4, cq = (t & 15) * 4;
        float4 v = *(const float4*)(AB + (size_t)(b * 64 + z * 16 + i) * 1024 + 512 + c0 + cq);
        *(float4*)&sB[i * 64 + cq] = v;
    }
    if (t < 64) sb1[t] = b1[c0 + t];
    __syncthreads();

    float av[64];
#pragma unroll
    for (int j = 0; j < 64; ++j) av[j] = sA[j * 64 + cl];
    float b1c = sb1[cl];
    float s = 0.f;
#pragma unroll
    for (int ii = 0; ii < 4; ++ii) {
        float base = sB[(ig * 4 + ii) * 64 + cl] + b1c;
#pragma unroll
        for (int j = 0; j < 64; ++j) s += fmaxf(base + av[j], 0.f);
    }
    sPart[ig][cl] = s;
    __syncthreads();
    if (t < 64) {
        float tot = sPart[0][t] + sPart[1][t] + sPart[2][t] + sPart[3][t];
        atomicAdd(&msum[b * 512 + c0 + t], tot);
    }
}

// out[b,o] = msum[b,:]/4096 . w2[o,:] + b2[o]
__global__ __launch_bounds__(256) void k_final(
    const float* __restrict__ msum, const float* __restrict__ w2,
    const float* __restrict__ b2, float* __restrict__ out)
{
    __shared__ float sm[512];
    int t = threadIdx.x;
    int b = blockIdx.x;
    int o = blockIdx.y * 256 + t;
    sm[t]       = msum[b * 512 + t]       * (1.f / 4096.f);
    sm[t + 256] = msum[b * 512 + 256 + t] * (1.f / 4096.f);
    __syncthreads();
    const float* wr = w2 + (size_t)o * 512;
    float acc = 0.f;
#pragma unroll 8
    for (int c = 0; c < 512; c += 4) {
        float4 w = *(const float4*)(wr + c);
        acc += sm[c] * w.x + sm[c + 1] * w.y + sm[c + 2] * w.z + sm[c + 3] * w.w;
    }
    out[b * 2048 + o] = acc + b2[o];
}

extern "C" void kernel_launch(void* const* d_in, const int* in_sizes, int n_in,
                              void* d_out, int out_size, void* d_ws, size_t ws_size,
                              hipStream_t stream)
{
    const float* x   = (const float*)d_in[0];
    const float* e1w = (const float*)d_in[1];
    const float* e1b = (const float*)d_in[2];
    const float* e2w = (const float*)d_in[3];
    const float* e2b = (const float*)d_in[4];
    const float* r1w = (const float*)d_in[5];
    const float* r1b = (const float*)d_in[6];
    const float* r2w = (const float*)d_in[7];
    const float* r2b = (const float*)d_in[8];
    const float* r3w = (const float*)d_in[9];
    const float* r3b = (const float*)d_in[10];
    const float* w1  = (const float*)d_in[11];
    const float* b1  = (const float*)d_in[12];
    const float* w2  = (const float*)d_in[13];
    const float* b2  = (const float*)d_in[14];
    float* out = (float*)d_out;

    float* ws   = (float*)d_ws;
    float* emb0 = ws;                     // 1024*128
    float* emb1 = emb0 + 1024 * 128;      // 1024*256
    float* emb2 = emb1 + 1024 * 256;      // 1024*512
    float* emb3 = emb2 + 1024 * 512;      // 1024*1024
    float* AB   = emb3 + 1024 * 1024;     // 1024*1024
    float* msum = AB   + 1024 * 1024;     // 16*512

    hipMemsetAsync(msum, 0, 16 * 512 * sizeof(float), stream);

    k_embed<<<512, 256, 0, stream>>>(x, e1w, e1b, e2w, e2b, emb0);
    // emb0(1024,128) @ r1w(256,128)^T -> emb1
    k_gemm<<<dim3(16, 4),  256, 0, stream>>>(emb0, r1w, r1b, emb1, 128, 256, 128, 1 << 30, 0, 1);
    // emb1 @ r2w(512,256)^T -> emb2
    k_gemm<<<dim3(16, 8),  256, 0, stream>>>(emb1, r2w, r2b, emb2, 256, 512, 256, 1 << 30, 0, 1);
    // emb2 @ r3w(1024,512)^T -> emb3
    k_gemm<<<dim3(16, 16), 256, 0, stream>>>(emb2, r3w, r3b, emb3, 512, 1024, 512, 1 << 30, 0, 1);
    // emb3 @ [w1a | w1b]^T -> AB (no bias/relu); w1 row stride 2048, B-half offset 1024
    k_gemm<<<dim3(16, 16), 256, 0, stream>>>(emb3, w1, nullptr, AB, 1024, 1024, 2048, 512, 1024, 0);
    // pairwise relu-mean accumulation
    k_pairmean<<<dim3(16, 8, 4), 256, 0, stream>>>(AB, b1, msum);
    // final projection
    k_final<<<dim3(16, 8), 256, 0, stream>>>(msum, w2, b2, out);
}

// Round 2
// 140.609 us; speedup vs baseline: 1.5309x; 1.5309x over previous
//
#include <hip/hip_runtime.h>

// ---------------------------------------------------------------------------
// keypoint_embedding, R1: bf16-MFMA GEMM stages, fp32 pairmean/final.
//   x(16,64,16) -> emb0b(1024,128)bf16 -> emb1b(1024,256) -> emb2b(1024,512)
//   -> emb3b(1024,1024) -> AB(1024,1024)fp32 [A=cols 0..511, B=512..1023]
//   -> msum(16,512) -> out(16,2048)
// Weights converted fp32->bf16 (RNE) per call; w1a/w1b split folded into wab.
// ---------------------------------------------------------------------------

typedef __attribute__((ext_vector_type(8))) short s16x8;      // 8 bf16 bits
typedef __attribute__((ext_vector_type(8))) unsigned short u16x8;
typedef __attribute__((ext_vector_type(4))) float f32x4;

static __device__ __forceinline__ unsigned short f2bf(float f) {
    unsigned u = __float_as_uint(f);
    u += 0x7fff + ((u >> 16) & 1);   // round-to-nearest-even
    return (unsigned short)(u >> 16);
}

// ---- embed: fp32 compute, bf16 store --------------------------------------
__global__ __launch_bounds__(256) void k_embed(
    const float* __restrict__ x,
    const float* __restrict__ e1w, const float* __restrict__ e1b,
    const float* __restrict__ e2w, const float* __restrict__ e2b,
    unsigned short* __restrict__ emb0b)
{
    int idx = blockIdx.x * 256 + threadIdx.x;   // 1024*128
    int row = idx >> 7, o = idx & 127;
    const float* xr = x + row * 16;
    float s1 = e1b[o] + xr[0] * e1w[o * 3 + 0] + xr[1] * e1w[o * 3 + 1] + xr[2] * e1w[o * 3 + 2];
    float s2 = e2b[o];
#pragma unroll
    for (int k = 0; k < 13; ++k) s2 += xr[3 + k] * e2w[o * 13 + k];
    emb0b[row * 128 + o] = f2bf(fmaxf(s1, 0.f) + fmaxf(s2, 0.f));
}

// ---- weight conversion fp32 -> bf16 (w1 split folded) ----------------------
__global__ __launch_bounds__(256) void k_convw(
    const float* __restrict__ r1w, const float* __restrict__ r2w,
    const float* __restrict__ r3w, const float* __restrict__ w1,
    unsigned short* __restrict__ r1b, unsigned short* __restrict__ r2b,
    unsigned short* __restrict__ r3b, unsigned short* __restrict__ wab)
{
    const int n1 = 256 * 128, n2 = 512 * 256, n3 = 1024 * 512; // then 1024*1024
    int i = (blockIdx.x * 256 + threadIdx.x) * 4;
    float4 v; unsigned short* dst; int j;
    if (i < n1)                { j = i;             v = *(const float4*)(r1w + j); dst = r1b + j; }
    else if (i < n1 + n2)      { j = i - n1;        v = *(const float4*)(r2w + j); dst = r2b + j; }
    else if (i < n1 + n2 + n3) { j = i - n1 - n2;   v = *(const float4*)(r3w + j); dst = r3b + j; }
    else {
        j = i - n1 - n2 - n3;                       // index into wab (1024x1024)
        int n = j >> 10, k = j & 1023;
        v = *(const float4*)(w1 + (size_t)(n & 511) * 2048 + (n >> 9) * 1024 + k);
        dst = wab + j;
    }
    ushort4 o; o.x = f2bf(v.x); o.y = f2bf(v.y); o.z = f2bf(v.z); o.w = f2bf(v.w);
    *(ushort4*)dst = o;
}

// ---- bf16 MFMA GEMM: C = act(A(M,K) @ W(N,K)^T + bias) ---------------------
// 64x64 block tile, 4 waves in 2x2, each wave 32x32 via 2x2 mfma 16x16x32.
// Out: bf16 (Cb) or fp32 (Cf).
__global__ __launch_bounds__(256) void k_mgemm(
    const unsigned short* __restrict__ A, const unsigned short* __restrict__ W,
    const float* __restrict__ bias, float* __restrict__ Cf,
    unsigned short* __restrict__ Cb, int K, int N, int relu)
{
    __shared__ unsigned short As[64 * 72];   // +8 pad: 2-way bank aliasing only
    __shared__ unsigned short Ws[64 * 72];
    int t = threadIdx.x;
    int m0 = blockIdx.x * 64, n0 = blockIdx.y * 64;
    int lane = t & 63, wv = t >> 6;
    int wm = (wv >> 1) * 32, wn = (wv & 1) * 32;
    int lr = lane & 15, quad = lane >> 4;

    f32x4 acc[2][2] = {};

    int srow = t >> 3;            // 0..31
    int scol = (t & 7) * 8;       // 0,8,..,56

    for (int k0 = 0; k0 < K; k0 += 64) {
        u16x8 a0 = *(const u16x8*)(A + (size_t)(m0 + srow) * K + k0 + scol);
        u16x8 a1 = *(const u16x8*)(A + (size_t)(m0 + srow + 32) * K + k0 + scol);
        u16x8 w0 = *(const u16x8*)(W + (size_t)(n0 + srow) * K + k0 + scol);
        u16x8 w1 = *(const u16x8*)(W + (size_t)(n0 + srow + 32) * K + k0 + scol);
        __syncthreads();                       // previous iter's reads done
        *(u16x8*)(As + srow * 72 + scol)        = a0;
        *(u16x8*)(As + (srow + 32) * 72 + scol) = a1;
        *(u16x8*)(Ws + srow * 72 + scol)        = w0;
        *(u16x8*)(Ws + (srow + 32) * 72 + scol) = w1;
        __syncthreads();
#pragma unroll
        for (int kk = 0; kk < 64; kk += 32) {
            s16x8 af[2], bfr[2];
#pragma unroll
            for (int mt = 0; mt < 2; ++mt)
                af[mt] = *(const s16x8*)(As + (wm + mt * 16 + lr) * 72 + kk + quad * 8);
#pragma unroll
            for (int nt = 0; nt < 2; ++nt)
                bfr[nt] = *(const s16x8*)(Ws + (wn + nt * 16 + lr) * 72 + kk + quad * 8);
#pragma unroll
            for (int mt = 0; mt < 2; ++mt)
#pragma unroll
                for (int nt = 0; nt < 2; ++nt)
                    acc[mt][nt] = __builtin_amdgcn_mfma_f32_16x16x32_bf16(
                        af[mt], bfr[nt], acc[mt][nt], 0, 0, 0);
        }
    }

#pragma unroll
    for (int mt = 0; mt < 2; ++mt)
#pragma unroll
        for (int nt = 0; nt < 2; ++nt) {
            int col = n0 + wn + nt * 16 + lr;
            float bv = bias ? bias[col] : 0.f;
#pragma unroll
            for (int r = 0; r < 4; ++r) {
                int row = m0 + wm + mt * 16 + quad * 4 + r;
                float v = acc[mt][nt][r] + bv;
                if (relu) v = fmaxf(v, 0.f);
                if (Cb) Cb[(size_t)row * N + col] = f2bf(v);
                else    Cf[(size_t)row * N + col] = v;
            }
        }
}

// ---- pairwise relu-mean accumulation (fp32, unchanged) ---------------------
__global__ __launch_bounds__(256) void k_pairmean(
    const float* __restrict__ AB, const float* __restrict__ b1,
    float* __restrict__ msum)
{
    __shared__ float sA[64 * 64];
    __shared__ float sB[16 * 64];
    __shared__ float sb1[64];
    __shared__ float sPart[4][64];
    int t = threadIdx.x;
    int b = blockIdx.x, c0 = blockIdx.y * 64, z = blockIdx.z;
    int cl = t & 63, ig = t >> 6;

#pragma unroll
    for (int rep = 0; rep < 4; ++rep) {
        int lin = rep * 256 + t;
        int j = lin >> 4, cq = (lin & 15) * 4;
        float4 v = *(const float4*)(AB + (size_t)(b * 64 + j) * 1024 + c0 + cq);
        *(float4*)&sA[j * 64 + cq] = v;
    }
    {
        int i = t >> 4, cq = (t & 15) * 4;
        float4 v = *(const float4*)(AB + (size_t)(b * 64 + z * 16 + i) * 1024 + 512 + c0 + cq);
        *(float4*)&sB[i * 64 + cq] = v;
    }
    if (t < 64) sb1[t] = b1[c0 + t];
    __syncthreads();

    float av[64];
#pragma unroll
    for (int j = 0; j < 64; ++j) av[j] = sA[j * 64 + cl];
    float b1c = sb1[cl];
    float s = 0.f;
#pragma unroll
    for (int ii = 0; ii < 4; ++ii) {
        float base = sB[(ig * 4 + ii) * 64 + cl] + b1c;
#pragma unroll
        for (int j = 0; j < 64; ++j) s += fmaxf(base + av[j], 0.f);
    }
    sPart[ig][cl] = s;
    __syncthreads();
    if (t < 64) {
        float tot = sPart[0][t] + sPart[1][t] + sPart[2][t] + sPart[3][t];
        atomicAdd(&msum[b * 512 + c0 + t], tot);
    }
}

// ---- final projection (fp32, unchanged) ------------------------------------
__global__ __launch_bounds__(256) void k_final(
    const float* __restrict__ msum, const float* __restrict__ w2,
    const float* __restrict__ b2, float* __restrict__ out)
{
    __shared__ float sm[512];
    int t = threadIdx.x;
    int b = blockIdx.x;
    int o = blockIdx.y * 256 + t;
    sm[t]       = msum[b * 512 + t]       * (1.f / 4096.f);
    sm[t + 256] = msum[b * 512 + 256 + t] * (1.f / 4096.f);
    __syncthreads();
    const float* wr = w2 + (size_t)o * 512;
    float acc = 0.f;
#pragma unroll 8
    for (int c = 0; c < 512; c += 4) {
        float4 w = *(const float4*)(wr + c);
        acc += sm[c] * w.x + sm[c + 1] * w.y + sm[c + 2] * w.z + sm[c + 3] * w.w;
    }
    out[b * 2048 + o] = acc + b2[o];
}

extern "C" void kernel_launch(void* const* d_in, const int* in_sizes, int n_in,
                              void* d_out, int out_size, void* d_ws, size_t ws_size,
                              hipStream_t stream)
{
    const float* x   = (const float*)d_in[0];
    const float* e1w = (const float*)d_in[1];
    const float* e1b = (const float*)d_in[2];
    const float* e2w = (const float*)d_in[3];
    const float* e2b = (const float*)d_in[4];
    const float* r1w = (const float*)d_in[5];
    const float* r1b = (const float*)d_in[6];
    const float* r2w = (const float*)d_in[7];
    const float* r2b = (const float*)d_in[8];
    const float* r3w = (const float*)d_in[9];
    const float* r3b = (const float*)d_in[10];
    const float* w1  = (const float*)d_in[11];
    const float* b1  = (const float*)d_in[12];
    const float* w2  = (const float*)d_in[13];
    const float* b2  = (const float*)d_in[14];
    float* out = (float*)d_out;

    // workspace layout (bf16 buffers first, then fp32)
    unsigned short* emb0b = (unsigned short*)d_ws;          // 1024*128
    unsigned short* emb1b = emb0b + 1024 * 128;             // 1024*256
    unsigned short* emb2b = emb1b + 1024 * 256;             // 1024*512
    unsigned short* emb3b = emb2b + 1024 * 512;             // 1024*1024
    unsigned short* r1wb  = emb3b + 1024 * 1024;            // 256*128
    unsigned short* r2wb  = r1wb  + 256 * 128;              // 512*256
    unsigned short* r3wb  = r2wb  + 512 * 256;              // 1024*512
    unsigned short* wab   = r3wb  + 1024 * 512;             // 1024*1024
    float* AB   = (float*)(wab + 1024 * 1024);              // 1024*1024 fp32
    float* msum = AB + 1024 * 1024;                         // 16*512

    hipMemsetAsync(msum, 0, 16 * 512 * sizeof(float), stream);

    // weight conversion: (32768+131072+524288+1048576)/4 = 434176 threads
    k_convw<<<1696, 256, 0, stream>>>(r1w, r2w, r3w, w1, r1wb, r2wb, r3wb, wab);
    k_embed<<<512, 256, 0, stream>>>(x, e1w, e1b, e2w, e2b, emb0b);

    // emb0b(1024,128) @ r1w^T -> emb1b
    k_mgemm<<<dim3(16, 4),  256, 0, stream>>>(emb0b, r1wb, r1b, nullptr, emb1b, 128, 256, 1);
    // emb1b @ r2w^T -> emb2b
    k_mgemm<<<dim3(16, 8),  256, 0, stream>>>(emb1b, r2wb, r2b, nullptr, emb2b, 256, 512, 1);
    // emb2b @ r3w^T -> emb3b
    k_mgemm<<<dim3(16, 16), 256, 0, stream>>>(emb2b, r3wb, r3b, nullptr, emb3b, 512, 1024, 1);
    // emb3b @ wab^T -> AB (fp32, no bias/relu)
    k_mgemm<<<dim3(16, 16), 256, 0, stream>>>(emb3b, wab, nullptr, AB, nullptr, 1024, 1024, 0);

    k_pairmean<<<dim3(16, 8, 4), 256, 0, stream>>>(AB, b1, msum);
    k_final<<<dim3(16, 8), 256, 0, stream>>>(msum, w2, b2, out);
}

// Round 3
// 132.656 us; speedup vs baseline: 1.6227x; 1.0600x over previous
//
#include <hip/hip_runtime.h>

// ---------------------------------------------------------------------------
// keypoint_embedding, R3: bf16-MFMA GEMMs with 32x64 tiles (2 blocks/CU on
// the big stages) + register prefetch of the next K-chunk; setup fused into
// one kernel (weight bf16 conversion + embed + msum zeroing). 7 dispatches.
// ---------------------------------------------------------------------------

typedef __attribute__((ext_vector_type(8))) short s16x8;
typedef __attribute__((ext_vector_type(8))) unsigned short u16x8;
typedef __attribute__((ext_vector_type(4))) float f32x4;

static __device__ __forceinline__ unsigned short f2bf(float f) {
    unsigned u = __float_as_uint(f);
    u += 0x7fff + ((u >> 16) & 1);   // round-to-nearest-even
    return (unsigned short)(u >> 16);
}

// ---- setup: convert weights to bf16, compute emb0 (bf16), zero msum -------
// blocks [0,1696): weight conversion (1696*1024 = 1,736,704 elements)
// blocks [1696,2208): embed (1024 rows x 128 cols)
// blocks [2208,2216): zero msum (16*512 floats)
__global__ __launch_bounds__(256) void k_setup(
    const float* __restrict__ x,
    const float* __restrict__ e1w, const float* __restrict__ e1b,
    const float* __restrict__ e2w, const float* __restrict__ e2b,
    const float* __restrict__ r1w, const float* __restrict__ r2w,
    const float* __restrict__ r3w, const float* __restrict__ w1,
    unsigned short* __restrict__ emb0b,
    unsigned short* __restrict__ r1wb, unsigned short* __restrict__ r2wb,
    unsigned short* __restrict__ r3wb, unsigned short* __restrict__ wab,
    float* __restrict__ msum)
{
    int blk = blockIdx.x;
    if (blk < 1696) {
        const int n1 = 256 * 128, n2 = 512 * 256, n3 = 1024 * 512;
        int i = (blk * 256 + threadIdx.x) * 4;
        float4 v; unsigned short* dst; int j;
        if (i < n1)                { j = i;           v = *(const float4*)(r1w + j); dst = r1wb + j; }
        else if (i < n1 + n2)      { j = i - n1;      v = *(const float4*)(r2w + j); dst = r2wb + j; }
        else if (i < n1 + n2 + n3) { j = i - n1 - n2; v = *(const float4*)(r3w + j); dst = r3wb + j; }
        else {
            j = i - n1 - n2 - n3;                    // index into wab (1024x1024)
            int n = j >> 10, k = j & 1023;
            v = *(const float4*)(w1 + (size_t)(n & 511) * 2048 + (n >> 9) * 1024 + k);
            dst = wab + j;
        }
        ushort4 o; o.x = f2bf(v.x); o.y = f2bf(v.y); o.z = f2bf(v.z); o.w = f2bf(v.w);
        *(ushort4*)dst = o;
    } else if (blk < 2208) {
        int idx = (blk - 1696) * 256 + threadIdx.x;  // 1024*128
        int row = idx >> 7, o = idx & 127;
        const float* xr = x + row * 16;
        float s1 = e1b[o] + xr[0] * e1w[o * 3 + 0] + xr[1] * e1w[o * 3 + 1] + xr[2] * e1w[o * 3 + 2];
        float s2 = e2b[o];
#pragma unroll
        for (int k = 0; k < 13; ++k) s2 += xr[3 + k] * e2w[o * 13 + k];
        emb0b[row * 128 + o] = f2bf(fmaxf(s1, 0.f) + fmaxf(s2, 0.f));
    } else {
        int i = ((blk - 2208) * 256 + threadIdx.x) * 4;   // 16*512 = 8192 floats
        float4 z = {0.f, 0.f, 0.f, 0.f};
        *(float4*)(msum + i) = z;
    }
}

// ---- bf16 MFMA GEMM: C = act(A(M,K) @ W(N,K)^T + bias) ---------------------
// 32x64 block tile, 256 threads = 4 waves in 2x2; wave-tile 16x32
// (1x2 mfma_f32_16x16x32_bf16 per 32-K chunk). Register prefetch of next
// K-chunk overlaps global latency with MFMA/ds_read.
__global__ __launch_bounds__(256) void k_mgemm(
    const unsigned short* __restrict__ A, const unsigned short* __restrict__ W,
    const float* __restrict__ bias, float* __restrict__ Cf,
    unsigned short* __restrict__ Cb, int K, int N, int relu)
{
    __shared__ unsigned short As[32 * 72];   // +8 pad
    __shared__ unsigned short Ws[64 * 72];
    int t = threadIdx.x;
    int m0 = blockIdx.x * 32, n0 = blockIdx.y * 64;
    int lane = t & 63, wv = t >> 6;
    int wm = (wv >> 1) * 16, wn = (wv & 1) * 32;
    int lr = lane & 15, quad = lane >> 4;

    f32x4 acc[2] = {};

    int srow = t >> 3;            // 0..31
    int scol = (t & 7) * 8;       // 0,8,..,56
    const unsigned short* Ap  = A + (size_t)(m0 + srow) * K + scol;
    const unsigned short* Wp0 = W + (size_t)(n0 + srow) * K + scol;
    const unsigned short* Wp1 = W + (size_t)(n0 + srow + 32) * K + scol;

    u16x8 ra = *(const u16x8*)Ap;
    u16x8 rw0 = *(const u16x8*)Wp0;
    u16x8 rw1 = *(const u16x8*)Wp1;

    for (int k0 = 0; k0 < K; k0 += 64) {
        __syncthreads();                       // prior iter's LDS reads done
        *(u16x8*)(As + srow * 72 + scol)        = ra;
        *(u16x8*)(Ws + srow * 72 + scol)        = rw0;
        *(u16x8*)(Ws + (srow + 32) * 72 + scol) = rw1;
        __syncthreads();
        if (k0 + 64 < K) {                     // prefetch next chunk (issue only)
            ra  = *(const u16x8*)(Ap  + k0 + 64);
            rw0 = *(const u16x8*)(Wp0 + k0 + 64);
            rw1 = *(const u16x8*)(Wp1 + k0 + 64);
        }
#pragma unroll
        for (int kk = 0; kk < 64; kk += 32) {
            s16x8 af  = *(const s16x8*)(As + (wm + lr) * 72 + kk + quad * 8);
            s16x8 bf0 = *(const s16x8*)(Ws + (wn + lr) * 72 + kk + quad * 8);
            s16x8 bf1 = *(const s16x8*)(Ws + (wn + 16 + lr) * 72 + kk + quad * 8);
            acc[0] = __builtin_amdgcn_mfma_f32_16x16x32_bf16(af, bf0, acc[0], 0, 0, 0);
            acc[1] = __builtin_amdgcn_mfma_f32_16x16x32_bf16(af, bf1, acc[1], 0, 0, 0);
        }
    }

#pragma unroll
    for (int nt = 0; nt < 2; ++nt) {
        int col = n0 + wn + nt * 16 + lr;
        float bv = bias ? bias[col] : 0.f;
#pragma unroll
        for (int r = 0; r < 4; ++r) {
            int row = m0 + wm + quad * 4 + r;
            float v = acc[nt][r] + bv;
            if (relu) v = fmaxf(v, 0.f);
            if (Cb) Cb[(size_t)row * N + col] = f2bf(v);
            else    Cf[(size_t)row * N + col] = v;
        }
    }
}

// ---- pairwise relu-mean accumulation (fp32) --------------------------------
__global__ __launch_bounds__(256) void k_pairmean(
    const float* __restrict__ AB, const float* __restrict__ b1,
    float* __restrict__ msum)
{
    __shared__ float sA[64 * 64];
    __shared__ float sB[16 * 64];
    __shared__ float sb1[64];
    __shared__ float sPart[4][64];
    int t = threadIdx.x;
    int b = blockIdx.x, c0 = blockIdx.y * 64, z = blockIdx.z;
    int cl = t & 63, ig = t >> 6;

#pragma unroll
    for (int rep = 0; rep < 4; ++rep) {
        int lin = rep * 256 + t;
        int j = lin >> 4, cq = (lin & 15) * 4;
        float4 v = *(const float4*)(AB + (size_t)(b * 64 + j) * 1024 + c0 + cq);
        *(float4*)&sA[j * 64 + cq] = v;
    }
    {
        int i = t >> 4, cq = (t & 15) * 4;
        float4 v = *(const float4*)(AB + (size_t)(b * 64 + z * 16 + i) * 1024 + 512 + c0 + cq);
        *(float4*)&sB[i * 64 + cq] = v;
    }
    if (t < 64) sb1[t] = b1[c0 + t];
    __syncthreads();

    float av[64];
#pragma unroll
    for (int j = 0; j < 64; ++j) av[j] = sA[j * 64 + cl];
    float b1c = sb1[cl];
    float s = 0.f;
#pragma unroll
    for (int ii = 0; ii < 4; ++ii) {
        float base = sB[(ig * 4 + ii) * 64 + cl] + b1c;
#pragma unroll
        for (int j = 0; j < 64; ++j) s += fmaxf(base + av[j], 0.f);
    }
    sPart[ig][cl] = s;
    __syncthreads();
    if (t < 64) {
        float tot = sPart[0][t] + sPart[1][t] + sPart[2][t] + sPart[3][t];
        atomicAdd(&msum[b * 512 + c0 + t], tot);
    }
}

// ---- final projection ------------------------------------------------------
__global__ __launch_bounds__(256) void k_final(
    const float* __restrict__ msum, const float* __restrict__ w2,
    const float* __restrict__ b2, float* __restrict__ out)
{
    __shared__ float sm[512];
    int t = threadIdx.x;
    int b = blockIdx.x;
    int o = blockIdx.y * 256 + t;
    sm[t]       = msum[b * 512 + t]       * (1.f / 4096.f);
    sm[t + 256] = msum[b * 512 + 256 + t] * (1.f / 4096.f);
    __syncthreads();
    const float* wr = w2 + (size_t)o * 512;
    float acc = 0.f;
#pragma unroll 8
    for (int c = 0; c < 512; c += 4) {
        float4 w = *(const float4*)(wr + c);
        acc += sm[c] * w.x + sm[c + 1] * w.y + sm[c + 2] * w.z + sm[c + 3] * w.w;
    }
    out[b * 2048 + o] = acc + b2[o];
}

extern "C" void kernel_launch(void* const* d_in, const int* in_sizes, int n_in,
                              void* d_out, int out_size, void* d_ws, size_t ws_size,
                              hipStream_t stream)
{
    const float* x   = (const float*)d_in[0];
    const float* e1w = (const float*)d_in[1];
    const float* e1b = (const float*)d_in[2];
    const float* e2w = (const float*)d_in[3];
    const float* e2b = (const float*)d_in[4];
    const float* r1w = (const float*)d_in[5];
    const float* r1b = (const float*)d_in[6];
    const float* r2w = (const float*)d_in[7];
    const float* r2b = (const float*)d_in[8];
    const float* r3w = (const float*)d_in[9];
    const float* r3b = (const float*)d_in[10];
    const float* w1  = (const float*)d_in[11];
    const float* b1  = (const float*)d_in[12];
    const float* w2  = (const float*)d_in[13];
    const float* b2  = (const float*)d_in[14];
    float* out = (float*)d_out;

    unsigned short* emb0b = (unsigned short*)d_ws;          // 1024*128
    unsigned short* emb1b = emb0b + 1024 * 128;             // 1024*256
    unsigned short* emb2b = emb1b + 1024 * 256;             // 1024*512
    unsigned short* emb3b = emb2b + 1024 * 512;             // 1024*1024
    unsigned short* r1wb  = emb3b + 1024 * 1024;            // 256*128
    unsigned short* r2wb  = r1wb  + 256 * 128;              // 512*256
    unsigned short* r3wb  = r2wb  + 512 * 256;              // 1024*512
    unsigned short* wab   = r3wb  + 1024 * 512;             // 1024*1024
    float* AB   = (float*)(wab + 1024 * 1024);              // 1024*1024 fp32
    float* msum = AB + 1024 * 1024;                         // 16*512

    k_setup<<<2216, 256, 0, stream>>>(x, e1w, e1b, e2w, e2b,
                                      r1w, r2w, r3w, w1,
                                      emb0b, r1wb, r2wb, r3wb, wab, msum);

    // emb0b(1024,128) @ r1w^T -> emb1b(1024,256)
    k_mgemm<<<dim3(32, 4),  256, 0, stream>>>(emb0b, r1wb, r1b, nullptr, emb1b, 128, 256, 1);
    // emb1b @ r2w^T -> emb2b(1024,512)
    k_mgemm<<<dim3(32, 8),  256, 0, stream>>>(emb1b, r2wb, r2b, nullptr, emb2b, 256, 512, 1);
    // emb2b @ r3w^T -> emb3b(1024,1024)
    k_mgemm<<<dim3(32, 16), 256, 0, stream>>>(emb2b, r3wb, r3b, nullptr, emb3b, 512, 1024, 1);
    // emb3b @ wab^T -> AB(1024,1024) fp32
    k_mgemm<<<dim3(32, 16), 256, 0, stream>>>(emb3b, wab, nullptr, AB, nullptr, 1024, 1024, 0);

    k_pairmean<<<dim3(16, 8, 4), 256, 0, stream>>>(AB, b1, msum);
    k_final<<<dim3(16, 8), 256, 0, stream>>>(msum, w2, b2, out);
}